// Round 1
// baseline (987.759 us; speedup 1.0000x reference)
//
#include <hip/hip_runtime.h>
#include <math.h>

#define B_ 16
#define CIN_ 3
#define HID_ 64
#define S_ 16384
#define MODES_ 16
#define HEADS_ 4
#define CH_ 16
#define ED_ 8
#define NPSP_ 500
#define NPFR_ 200
#define LAYERS_ 4

// ---------------------------------------------------------------------------
// Lift: h[b,d,s] = sum_c x[b,c,s]*W[c,d] + bias[d]   (store h as f32, sC f64)
// ---------------------------------------------------------------------------
__global__ __launch_bounds__(256) void k_lift(const float* __restrict__ x,
                                              const float* __restrict__ W,
                                              const float* __restrict__ bias,
                                              float* __restrict__ h,
                                              double* __restrict__ sC) {
    int b = blockIdx.y;
    int s = blockIdx.x * 256 + threadIdx.x;
    const float* xb = x + (size_t)b * CIN_ * S_ + s;
    double x0 = (double)xb[0];
    double x1 = (double)xb[S_];
    double x2 = (double)xb[2 * S_];
    float* hb = h + (size_t)b * HID_ * S_ + s;
    double acc = 0.0;
    for (int d = 0; d < HID_; ++d) {
        double v = x0 * (double)W[d];
        v = fma(x1, (double)W[HID_ + d], v);
        v = fma(x2, (double)W[2 * HID_ + d], v);
        v += (double)bias[d];
        hb[(size_t)d * S_] = (float)v;
        acc += v;   // channel sum from UNROUNDED values (hash-sensitive)
    }
    sC[(size_t)b * S_ + s] = acc;
}

// ---------------------------------------------------------------------------
// Spatial hash: wsum over replicate-padded window, idx, and sum of gathered
// embeddings (Ebar) for the mean path.
// ---------------------------------------------------------------------------
__global__ __launch_bounds__(256) void k_hash(const double* __restrict__ sC,
                                              const float* __restrict__ emb_l,
                                              int* __restrict__ idx,
                                              double* __restrict__ Eb) {
    int b = blockIdx.y;
    int s0 = blockIdx.x * 256;
    int t = threadIdx.x;
    __shared__ double sl[260];
    for (int j = t; j < 260; j += 256) {
        int p = s0 - 2 + j;
        p = p < 0 ? 0 : (p > S_ - 1 ? S_ - 1 : p);
        sl[j] = sC[(size_t)b * S_ + p];
    }
    __syncthreads();
    // reference order: ((a+b)+c)+d
    double wsum = ((sl[t] + sl[t + 1]) + sl[t + 2]) + sl[t + 3];
    int ti = (int)(wsum * 31.0);         // trunc toward zero, like astype(int32)
    int id = ti % NPSP_;
    if (id < 0) id += NPSP_;             // python floor-mod
    idx[(size_t)b * S_ + s0 + t] = id;

    const float* er = emb_l + id * ED_;
    double ev[8];
#pragma unroll
    for (int k = 0; k < 8; k++) ev[k] = (double)er[k];

    int lane = t & 63, wv = t >> 6;
    __shared__ double red[4][8];
#pragma unroll
    for (int k = 0; k < 8; k++) {
        double v = ev[k];
        for (int off = 32; off > 0; off >>= 1) v += __shfl_down(v, off, 64);
        if (lane == 0) red[wv][k] = v;
    }
    __syncthreads();
    if (t < 8) {
        double v = red[0][t] + red[1][t] + red[2][t] + red[3][t];
        atomicAdd(&Eb[b * ED_ + t], v);
    }
}

// ---------------------------------------------------------------------------
// 16-mode direct DFT over S for a pair of channels per block.
// Xr = sum h*cos(2*pi*m*s/S); Xi = -sum h*sin(...)  (rfft convention)
// ---------------------------------------------------------------------------
__global__ __launch_bounds__(256) void k_dft(const float* __restrict__ h,
                                             double* __restrict__ Xr,
                                             double* __restrict__ Xi) {
    int b = blockIdx.y;
    int c0 = blockIdx.x * 2;
    int t = threadIdx.x;
    const float* h0 = h + ((size_t)(b * HID_ + c0)) * S_;
    const float* h1 = h0 + S_;

    double acc[64];
#pragma unroll
    for (int k = 0; k < 64; k++) acc[k] = 0.0;

    // base twiddle for s = t: angle 2*pi*s/S = pi * (s/8192)
    double cb = cospi((double)t / 8192.0);
    double sb = sinpi((double)t / 8192.0);
    // rotation per s += 256: 2*pi*256/S = pi/32
    const double CD = 0.99518472667219688624;  // cos(pi/32)
    const double SD = 0.09801714032956060199;  // sin(pi/32)

    for (int k = 0; k < 64; k++) {
        int s = t + (k << 8);
        double hv0 = (double)h0[s];
        double hv1 = (double)h1[s];
        acc[0] += hv0;
        acc[32] += hv1;
        double c = cb, sv = sb;
#pragma unroll
        for (int m = 1; m < 16; m++) {
            acc[m]      = fma(hv0, c,  acc[m]);
            acc[16 + m] = fma(hv0, sv, acc[16 + m]);
            acc[32 + m] = fma(hv1, c,  acc[32 + m]);
            acc[48 + m] = fma(hv1, sv, acc[48 + m]);
            double cn = c * cb - sv * sb;
            double sn = sv * cb + c * sb;
            c = cn; sv = sn;
        }
        double c2 = cb * CD - sb * SD;
        double s2 = sb * CD + cb * SD;
        cb = c2; sb = s2;
    }

    int lane = t & 63, wv = t >> 6;
    __shared__ double red[4][64];
#pragma unroll
    for (int k = 0; k < 64; k++) {
        double v = acc[k];
        for (int off = 32; off > 0; off >>= 1) v += __shfl_down(v, off, 64);
        if (lane == 0) red[wv][k] = v;
    }
    __syncthreads();
    if (t < 64) {
        double v = red[0][t] + red[1][t] + red[2][t] + red[3][t];
        int cc = t >> 5, im = (t >> 4) & 1, m = t & 15;
        int c = c0 + cc;
        if (im) Xi[((size_t)b * HID_ + c) * MODES_ + m] = -v;
        else    Xr[((size_t)b * HID_ + c) * MODES_ + m] = v;
    }
}

// ---------------------------------------------------------------------------
// Per-batch small stage: mag/fidx, MX (complex head mixing), P (spectral
// engram coeffs), means, gating MLP + softmax.
// ---------------------------------------------------------------------------
__global__ __launch_bounds__(256) void k_small(const double* __restrict__ Xr,
                                               const double* __restrict__ Xi,
                                               const float* __restrict__ mWr,
                                               const float* __restrict__ mWi,
                                               const float* __restrict__ fr_emb_l,
                                               const float* __restrict__ fr_W_l,
                                               const float* __restrict__ fr_b_l,
                                               const double* __restrict__ Eb,
                                               const float* __restrict__ sp_W_l,
                                               const float* __restrict__ sp_b_l,
                                               const float* __restrict__ gW1,
                                               const float* __restrict__ gb1,
                                               const float* __restrict__ gW2,
                                               const float* __restrict__ gb2,
                                               double* __restrict__ MXr,
                                               double* __restrict__ MXi,
                                               double* __restrict__ P,
                                               double* __restrict__ wgt) {
    int b = blockIdx.x;
    int t = threadIdx.x;
    __shared__ double sXr[HID_ * MODES_], sXi[HID_ * MODES_];
    __shared__ double sMr[HID_ * MODES_], sMi[HID_ * MODES_], sP[HID_ * MODES_];
    __shared__ double gg[192], h1s[64];
    __shared__ int magI[MODES_];
    __shared__ int fidxS;

    for (int j = t; j < HID_ * MODES_; j += 256) {
        sXr[j] = Xr[(size_t)b * HID_ * MODES_ + j];
        sXi[j] = Xi[(size_t)b * HID_ * MODES_ + j];
    }
    __syncthreads();

    // mag over channels (mean axis=1), truncate
    if (t < MODES_) {
        double acc = 0.0;
        for (int c = 0; c < HID_; c++) {
            double re = sXr[c * MODES_ + t], im = sXi[c * MODES_ + t];
            acc += sqrt(re * re + im * im);
        }
        double mag = acc * (1.0 / 64.0);
        magI[t] = (int)(mag * 1000.0);
    }

    // MX: of[b,h,o,m] = sum_i xh[b,h,i,m] * (Wr + iWi)[h,i,o,m]
    for (int u = t; u < HID_ * MODES_; u += 256) {
        int hh = u >> 8, rem = u & 255, o = rem >> 4, m = rem & 15;
        double aR = 0.0, aI = 0.0;
        for (int i = 0; i < CH_; i++) {
            int ci = hh * CH_ + i;
            double xr = sXr[ci * MODES_ + m];
            double xi = sXi[ci * MODES_ + m];
            double wr = (double)mWr[((size_t)(hh * CH_ + i) * CH_ + o) * MODES_ + m];
            double wi = (double)mWi[((size_t)(hh * CH_ + i) * CH_ + o) * MODES_ + m];
            aR += xr * wr - xi * wi;
            aI += xr * wi + xi * wr;
        }
        int co = hh * CH_ + o;
        sMr[co * MODES_ + m] = aR;
        sMi[co * MODES_ + m] = aI;
        MXr[(size_t)b * HID_ * MODES_ + co * MODES_ + m] = aR;
        MXi[(size_t)b * HID_ * MODES_ + co * MODES_ + m] = aI;
    }
    __syncthreads();

    if (t == 0) {
        int ssum = 0;
        for (int m = 0; m < MODES_; m++) ssum += magI[m];
        int f = ssum % NPFR_;
        if (f < 0) f += NPFR_;
        fidxS = f;
    }
    __syncthreads();

    // P[c,m] = fr_emb[fidx] @ fr_W[:, c*16+m] + fr_b
    {
        const float* fe = fr_emb_l + fidxS * ED_;
        for (int u = t; u < HID_ * MODES_; u += 256) {
            double acc = 0.0;
            for (int e = 0; e < ED_; e++)
                acc += (double)fe[e] * (double)fr_W_l[e * (HID_ * MODES_) + u];
            acc += (double)fr_b_l[u];
            sP[u] = acc;
            P[(size_t)b * HID_ * MODES_ + u] = acc;
        }
    }
    __syncthreads();

    // gating vector: [spmean | mhmean | frmean]
    if (t < 64) {
        double a = 0.0;
        for (int e = 0; e < ED_; e++)
            a += Eb[b * ED_ + e] * (double)sp_W_l[e * 64 + t];
        gg[t]       = a * (1.0 / 16384.0) + (double)sp_b_l[t];
        gg[64 + t]  = sMr[t * MODES_ + 0] * (1.0 / 16384.0);
        gg[128 + t] = sP[t * MODES_ + 0] * (1.0 / 16384.0);
    }
    __syncthreads();
    if (t < 64) {
        double a = 0.0;
        for (int k = 0; k < 192; k++) a += gg[k] * (double)gW1[k * 64 + t];
        a += (double)gb1[t];
        h1s[t] = a > 0.0 ? a : 0.0;
    }
    __syncthreads();
    if (t == 0) {
        double l[3];
        for (int j = 0; j < 3; j++) {
            double a = 0.0;
            for (int k = 0; k < 64; k++) a += h1s[k] * (double)gW2[k * 3 + j];
            l[j] = a + (double)gb2[j];
        }
        double mx = fmax(l[0], fmax(l[1], l[2]));
        double e0 = exp(l[0] - mx), e1 = exp(l[1] - mx), e2 = exp(l[2] - mx);
        double sum = e0 + e1 + e2;
        wgt[b * 4 + 0] = e0 / sum;
        wgt[b * 4 + 1] = e1 / sum;
        wgt[b * 4 + 2] = e2 / sum;
    }
}

// ---------------------------------------------------------------------------
// Reconstruction: thread = one (b,s); computes all 64 channels:
// sp (gather-dot), mh (31-term inverse DFT), fr (16-term cosine), gated gelu.
// Writes h (f32) and next-layer channel sum sC (f64, unrounded).
// ---------------------------------------------------------------------------
__global__ __launch_bounds__(256) void k_recon(const int* __restrict__ idx,
                                               const float* __restrict__ sp_emb_l,
                                               const float* __restrict__ sp_W_l,
                                               const float* __restrict__ sp_b_l,
                                               const double* __restrict__ MXr,
                                               const double* __restrict__ MXi,
                                               const double* __restrict__ P,
                                               const double* __restrict__ wgt,
                                               float* __restrict__ h,
                                               double* __restrict__ sC) {
    int b = blockIdx.y;
    int s0 = blockIdx.x * 256;
    int t = threadIdx.x;
    __shared__ double sMr[HID_ * MODES_], sMi[HID_ * MODES_], sP[HID_ * MODES_];
    __shared__ float semb[NPSP_ * 9];   // padded stride 9 vs bank conflicts
    __shared__ float sW[8 * 64];
    __shared__ float sbb[64];
    __shared__ double sw[3];

    for (int j = t; j < HID_ * MODES_; j += 256) {
        sMr[j] = MXr[(size_t)b * HID_ * MODES_ + j];
        sMi[j] = MXi[(size_t)b * HID_ * MODES_ + j];
        sP[j]  = P[(size_t)b * HID_ * MODES_ + j];
    }
    for (int j = t; j < NPSP_ * 8; j += 256) {
        int r = j >> 3, e = j & 7;
        semb[r * 9 + e] = sp_emb_l[j];
    }
    for (int j = t; j < 512; j += 256) sW[j] = sp_W_l[j];
    if (t < 64) sbb[t] = sp_b_l[t];
    if (t < 3) sw[t] = wgt[b * 4 + t];
    __syncthreads();

    int s = s0 + t;
    int id = idx[(size_t)b * S_ + s];
    double e[8];
#pragma unroll
    for (int k = 0; k < 8; k++) e[k] = (double)semb[id * 9 + k];

    double cb = cospi((double)s / 8192.0);
    double sb = sinpi((double)s / 8192.0);
    double cm[16], sm[16];
    cm[0] = 1.0; sm[0] = 0.0;
    cm[1] = cb;  sm[1] = sb;
#pragma unroll
    for (int m = 2; m < 16; m++) {
        cm[m] = cm[m - 1] * cb - sm[m - 1] * sb;
        sm[m] = sm[m - 1] * cb + cm[m - 1] * sb;
    }

    double w0 = sw[0], w1 = sw[1], w2 = sw[2];
    float* hb = h + (size_t)b * HID_ * S_ + s;
    double csum = 0.0;
    for (int c = 0; c < HID_; c++) {
        double spv = 0.0;
#pragma unroll
        for (int k = 0; k < 8; k++) spv += e[k] * (double)sW[k * 64 + c];
        spv += (double)sbb[c];

        const double* mr = sMr + c * MODES_;
        const double* mi = sMi + c * MODES_;
        const double* pp = sP + c * MODES_;
        double am = 0.0, af = 0.0;
#pragma unroll
        for (int m = 1; m < 16; m++) {
            am += mr[m] * cm[m] - mi[m] * sm[m];
            af += pp[m] * cm[m];
        }
        double mh  = (mr[0] + 2.0 * am) * (1.0 / 16384.0);
        double frv = (pp[0] + 2.0 * af) * (1.0 / 16384.0);
        double v = w0 * spv + w1 * mh + w2 * frv;
        double g = 0.5 * v * (1.0 + erf(v * 0.70710678118654752440));
        hb[(size_t)c * S_] = (float)g;
        csum += g;   // unrounded channel sum for the next layer's hash
    }
    sC[(size_t)b * S_ + s] = csum;
}

// ---------------------------------------------------------------------------
// Projection: out[b,s] = sum_d h[b,d,s]*pW[d] + pb
// ---------------------------------------------------------------------------
__global__ __launch_bounds__(256) void k_proj(const float* __restrict__ h,
                                              const float* __restrict__ pW,
                                              const float* __restrict__ pb,
                                              float* __restrict__ out) {
    int b = blockIdx.y;
    int s = blockIdx.x * 256 + threadIdx.x;
    const float* hb = h + (size_t)b * HID_ * S_ + s;
    double acc = 0.0;
    for (int d = 0; d < HID_; d++)
        acc += (double)hb[(size_t)d * S_] * (double)pW[d];
    out[(size_t)b * S_ + s] = (float)(acc + (double)pb[0]);
}

extern "C" void kernel_launch(void* const* d_in, const int* in_sizes, int n_in,
                              void* d_out, int out_size, void* d_ws, size_t ws_size,
                              hipStream_t stream) {
    const float* x      = (const float*)d_in[0];
    const float* lift_W = (const float*)d_in[1];
    const float* lift_b = (const float*)d_in[2];
    const float* proj_W = (const float*)d_in[3];
    const float* proj_b = (const float*)d_in[4];
    const float* sp_emb = (const float*)d_in[5];
    const float* sp_W   = (const float*)d_in[6];
    const float* sp_b   = (const float*)d_in[7];
    const float* fr_emb = (const float*)d_in[8];
    const float* fr_W   = (const float*)d_in[9];
    const float* fr_b   = (const float*)d_in[10];
    const float* g_W1   = (const float*)d_in[11];
    const float* g_b1   = (const float*)d_in[12];
    const float* g_W2   = (const float*)d_in[13];
    const float* g_b2   = (const float*)d_in[14];
    const float* mhf_Wr = (const float*)d_in[15];
    const float* mhf_Wi = (const float*)d_in[16];

    char* ws = (char*)d_ws;
    float* h   = (float*)ws;  ws += (size_t)B_ * HID_ * S_ * 4;   // 64 MiB
    double* sC = (double*)ws; ws += (size_t)B_ * S_ * 8;          // 2 MiB
    int* idx   = (int*)ws;    ws += (size_t)B_ * S_ * 4;          // 1 MiB
    double* Xr  = (double*)ws; ws += (size_t)B_ * HID_ * MODES_ * 8;
    double* Xi  = (double*)ws; ws += (size_t)B_ * HID_ * MODES_ * 8;
    double* MXr = (double*)ws; ws += (size_t)B_ * HID_ * MODES_ * 8;
    double* MXi = (double*)ws; ws += (size_t)B_ * HID_ * MODES_ * 8;
    double* P   = (double*)ws; ws += (size_t)B_ * HID_ * MODES_ * 8;
    double* Eb  = (double*)ws; ws += (size_t)LAYERS_ * B_ * ED_ * 8;
    double* wgt = (double*)ws; ws += (size_t)B_ * 4 * 8;

    hipMemsetAsync(Eb, 0, (size_t)LAYERS_ * B_ * ED_ * 8, stream);

    dim3 blk(256);
    k_lift<<<dim3(S_ / 256, B_), blk, 0, stream>>>(x, lift_W, lift_b, h, sC);

    for (int lay = 0; lay < LAYERS_; ++lay) {
        k_hash<<<dim3(S_ / 256, B_), blk, 0, stream>>>(
            sC, sp_emb + (size_t)lay * NPSP_ * ED_, idx, Eb + (size_t)lay * B_ * ED_);
        k_dft<<<dim3(HID_ / 2, B_), blk, 0, stream>>>(h, Xr, Xi);
        k_small<<<dim3(B_), blk, 0, stream>>>(
            Xr, Xi,
            mhf_Wr + (size_t)lay * HEADS_ * CH_ * CH_ * MODES_,
            mhf_Wi + (size_t)lay * HEADS_ * CH_ * CH_ * MODES_,
            fr_emb + (size_t)lay * NPFR_ * ED_,
            fr_W + (size_t)lay * ED_ * HID_ * MODES_,
            fr_b + (size_t)lay * HID_ * MODES_,
            Eb + (size_t)lay * B_ * ED_,
            sp_W + (size_t)lay * ED_ * HID_,
            sp_b + (size_t)lay * HID_,
            g_W1 + (size_t)lay * 192 * 64,
            g_b1 + (size_t)lay * 64,
            g_W2 + (size_t)lay * 64 * 3,
            g_b2 + (size_t)lay * 3,
            MXr, MXi, P, wgt);
        k_recon<<<dim3(S_ / 256, B_), blk, 0, stream>>>(
            idx,
            sp_emb + (size_t)lay * NPSP_ * ED_,
            sp_W + (size_t)lay * ED_ * HID_,
            sp_b + (size_t)lay * HID_,
            MXr, MXi, P, wgt, h, sC);
    }

    k_proj<<<dim3(S_ / 256, B_), blk, 0, stream>>>(h, proj_W, proj_b, (float*)d_out);
}